// Round 1
// 856.924 us; speedup vs baseline: 1.0492x; 1.0492x over previous
//
#include <hip/hip_runtime.h>
#include <hip/hip_bf16.h>

// vector_attention: S=2048, B=32, D=256, H=4. fp32 accumulate.
// Round 6: XCD-pair swizzle (tileM pairs share one XCD's L2 -> halve A fetch),
// double-buffered K-loop (stage t+1 overlaps compute t). Else as Round 5:
// 64x128 tiles, global_load_lds staging, 16-copy spread stats atomics,
// weights pre-converted to bf16 once, q+v projections batched.

typedef short  s16x8 __attribute__((ext_vector_type(8)));
typedef float  f32x4 __attribute__((ext_vector_type(4)));
typedef unsigned short u16;

constexpr int NC = 16;   // stat shadow copies

__device__ __forceinline__ float bu2f(u16 u) {
    union { unsigned int i; float f; } c; c.i = ((unsigned int)u) << 16; return c.f;
}
__device__ __forceinline__ float bs2f(short s) { return bu2f((u16)s); }
__device__ __forceinline__ u16 f2bu(float f) {  // RNE
    union { float f; unsigned int i; } c; c.f = f;
    unsigned int u = c.i;
    u += 0x7fffu + ((u >> 16) & 1u);
    return (u16)(u >> 16);
}
__device__ __forceinline__ unsigned int pack2(float a, float b) {  // v_cvt_pk_bf16_f32
    __hip_bfloat162 h = __float22bfloat162_rn(make_float2(a, b));
    union { __hip_bfloat162 h; unsigned int u; } c; c.h = h; return c.u;
}

// ---------------------------------------------------------------------------
// Dtype probe on q (first 64 KB). flag=1 bf16, 0 f32.
// ---------------------------------------------------------------------------
__global__ __launch_bounds__(256) void detect_k(const unsigned int* __restrict__ qw,
                                                int* __restrict__ flag)
{
    __shared__ int cnt[256];
    const int t = threadIdx.x;
    int c = 0;
    for (int i = 0; i < 64; i++) {
        const unsigned int w = qw[t + i * 256];
        const unsigned int e = (w >> 7) & 0xFFu;
        c += (e >= 96u && e <= 141u) ? 1 : 0;
    }
    cnt[t] = c;
    __syncthreads();
    for (int s = 128; s > 0; s >>= 1) {
        if (t < s) cnt[t] += cnt[t + s];
        __syncthreads();
    }
    if (t == 0) *flag = (cnt[0] > 8192) ? 1 : 0;
}

// ---------------------------------------------------------------------------
// Weight pre-convert: 5 tensors x [4,256,256] -> bf16 in ws.
// ---------------------------------------------------------------------------
__global__ __launch_bounds__(256) void wconv_k(
    const void* w0, const void* w1, const void* w2, const void* w3, const void* w4,
    const int* __restrict__ dflag, u16* __restrict__ dst)
{
    const void* srcs[5] = {w0, w1, w2, w3, w4};
    const int y = blockIdx.y;
    const int idx = blockIdx.x * 1024 + threadIdx.x * 4;
    u16* d = dst + y * 262144 + idx;
    if (*dflag == 0) {
        f32x4 v = *(const f32x4*)((const float*)srcs[y] + idx);
        unsigned int lo = pack2(v[0], v[1]);
        unsigned int hi = pack2(v[2], v[3]);
        *(unsigned long long*)d = ((unsigned long long)hi << 32) | lo;
    } else {
        *(unsigned long long*)d = *(const unsigned long long*)((const u16*)srcs[y] + idx);
    }
}

// ---------------------------------------------------------------------------
// GEMM core: C[65536,256] = op(A) @ W[256,256]^T + bias. Tile 64(M)x128(N),
// BK=32, 4 waves (2x2), wave = 32x64 (2x4 MFMA 16x16x32 bf16).
// AM 0: a=A (EXTA: external, f32-capable). AM 1: a=relu((A-A2)*sc+sh).
// AM 2: a=relu(A*sc+sh). AM>0 reduces NC-copy stats in prologue -> sc/sh.
// STATS 1: epilogue stats of (C - Qd); STATS 2: stats of C. 16-copy atomics.
// Grid must be 2048 in x. XCD-pair swizzle: work = (bx&7)*256 + (bx>>3) so
// the two tileN blocks sharing a tileM run adjacently on ONE XCD (A L2-hit).
// K-loop double-buffered: stage(t+1) issued before compute(t); one barrier/step.
// ---------------------------------------------------------------------------
template<int AM, bool EXTA, int STATS>
__device__ __forceinline__ void gemm_core(
    const u16* __restrict__ A, const float* __restrict__ Af,
    const u16* __restrict__ A2, const u16* __restrict__ Qd,
    const u16* __restrict__ Wb,
    const u16* __restrict__ bias16, const float* __restrict__ biasf,
    const u16* __restrict__ g16, const float* __restrict__ gf,
    const u16* __restrict__ be16, const float* __restrict__ bef,
    const float* __restrict__ statsIn, float* __restrict__ statsOut,
    const int f32in, u16* __restrict__ C, const int bx)
{
    // 2 x (As 2048 | Bs 4096) u16 = 24 KB; epilogue Cs 64x128 (16 KB) aliases.
    __shared__ __align__(16) u16 smem[12288];
    __shared__ float sc_s[256], sh_s[256];
    __shared__ float red_s[256];

    const int tid   = threadIdx.x;
    // XCD-pair swizzle (grid 2048, 8 XCDs, 256 works per XCD)
    const int work  = ((bx & 7) << 8) | (bx >> 3);
    const int tileN = work & 1;
    const int tileM = work >> 1;
    const int lane  = tid & 63;
    const int wave  = tid >> 6;
    const int wm    = wave & 1;
    const int wn    = wave >> 1;
    const int lrow  = lane & 15;
    const int quad  = lane >> 4;

    if constexpr (AM != 0) {
        const int c = tid;
        float s = 0.f, q = 0.f;
#pragma unroll
        for (int i = 0; i < NC; i++) {
            s += statsIn[i * 256 + c];
            q += statsIn[(NC + i) * 256 + c];
        }
        const float mean = s * (1.f / 65536.f);
        const float var  = q * (1.f / 65536.f) - mean * mean;
        const float rstd = rsqrtf(var + 1e-5f);
        const float gg = f32in ? gf[c] : bu2f(g16[c]);
        const float bb = f32in ? bef[c] : bu2f(be16[c]);
        sc_s[c] = rstd * gg;
        sh_s[c] = bb - mean * rstd * gg;
        __syncthreads();
    }

    f32x4 acc[2][4];
#pragma unroll
    for (int i = 0; i < 2; i++)
#pragma unroll
        for (int j = 0; j < 4; j++) acc[i][j] = (f32x4){0.f, 0.f, 0.f, 0.f};

    const int  rA   = tid >> 2;        // 0..63
    const int  kq   = (tid & 3) << 3;  // 0,8,16,24
    const long rowA = (long)tileM * 64;
    const int  rowB = tileN * 128;

    // stage K-tile k0 into buffer b
    auto stage = [&](int k0, int b) {
        u16* As = smem + b * 6144;
        u16* Bs = As + 2048;
        const u16* gw = Wb + (rowB + rA) * 256 + k0 + kq;
        __builtin_amdgcn_global_load_lds(
            (const __attribute__((address_space(1))) void*)gw,
            (__attribute__((address_space(3))) void*)(Bs + tid * 8), 16, 0, 0);
        __builtin_amdgcn_global_load_lds(
            (const __attribute__((address_space(1))) void*)(gw + 64 * 256),
            (__attribute__((address_space(3))) void*)(Bs + 2048 + tid * 8), 16, 0, 0);
        const long offA = (rowA + rA) * 256 + k0 + kq;
        if constexpr (AM == 0) {
            if (EXTA && f32in) {
                const float* p = Af + offA;
                f32x4 a = *(const f32x4*)p;
                f32x4 bb = *(const f32x4*)(p + 4);
                union { s16x8 v; unsigned int w[4]; } o;
                o.w[0] = pack2(a[0], a[1]); o.w[1] = pack2(a[2], a[3]);
                o.w[2] = pack2(bb[0], bb[1]); o.w[3] = pack2(bb[2], bb[3]);
                *(s16x8*)(As + tid * 8) = o.v;
            } else {
                __builtin_amdgcn_global_load_lds(
                    (const __attribute__((address_space(1))) void*)(A + offA),
                    (__attribute__((address_space(3))) void*)(As + tid * 8), 16, 0, 0);
            }
        } else {
            s16x8 xv = *(const s16x8*)(A + offA);
            s16x8 yv;
            if constexpr (AM == 1) yv = *(const s16x8*)(A2 + offA);
            float d[8];
#pragma unroll
            for (int e = 0; e < 8; e++) {
                float x = bs2f(xv[e]);
                if constexpr (AM == 1) x -= bs2f(yv[e]);
                d[e] = fmaxf(fmaf(x, sc_s[k0 + kq + e], sh_s[k0 + kq + e]), 0.f);
            }
            union { s16x8 v; unsigned int w[4]; } o;
            o.w[0] = pack2(d[0], d[1]); o.w[1] = pack2(d[2], d[3]);
            o.w[2] = pack2(d[4], d[5]); o.w[3] = pack2(d[6], d[7]);
            *(s16x8*)(As + tid * 8) = o.v;
        }
    };

    // compute K-tile from buffer b
    auto comp = [&](int b) {
        const u16* As = smem + b * 6144;
        const u16* Bs = As + 2048;
        s16x8 af[2], bf[4];
#pragma unroll
        for (int im = 0; im < 2; im++)
            af[im] = *(const s16x8*)(As + (wm * 32 + im * 16 + lrow) * 32 + quad * 8);
#pragma unroll
        for (int in = 0; in < 4; in++)
            bf[in] = *(const s16x8*)(Bs + (wn * 64 + in * 16 + lrow) * 32 + quad * 8);
#pragma unroll
        for (int im = 0; im < 2; im++)
#pragma unroll
            for (int in = 0; in < 4; in++)
                acc[im][in] = __builtin_amdgcn_mfma_f32_16x16x32_bf16(
                    af[im], bf[in], acc[im][in], 0, 0, 0);
    };

    // double-buffered main loop: stage(t+1) overlaps comp(t)
    stage(0, 0);
    __syncthreads();
    int cur = 0;
#pragma unroll
    for (int t = 0; t < 7; ++t) {
        stage((t + 1) * 32, cur ^ 1);
        comp(cur);
        __syncthreads();
        cur ^= 1;
    }
    comp(cur);

    // epilogue: C/D layout col=lane&15, row=quad*4+reg [m89/m91]; stage in LDS
    __syncthreads();
    u16* Cs = smem;   // 64 x 128
#pragma unroll
    for (int in = 0; in < 4; in++) {
        const int col  = wn * 64 + in * 16 + lrow;
        const int gcol = rowB + col;
        const float bv = f32in ? biasf[gcol] : bu2f(bias16[gcol]);
#pragma unroll
        for (int im = 0; im < 2; im++) {
            const int r0 = wm * 32 + im * 16 + quad * 4;
#pragma unroll
            for (int e = 0; e < 4; e++)
                Cs[(r0 + e) * 128 + col] = f2bu(acc[im][in][e] + bv);
        }
    }
    __syncthreads();

    if constexpr (STATS != 0) {
        const int colL = tid & 127;
        const int half = tid >> 7;
        float s = 0.f, qs = 0.f;
#pragma unroll 4
        for (int r = half * 32; r < half * 32 + 32; r++) {
            float x = bu2f(Cs[r * 128 + colL]);
            if constexpr (STATS == 1) x -= bu2f(Qd[(rowA + r) * 256 + rowB + colL]);
            s += x; qs += x * x;
        }
        red_s[tid] = s;
        __syncthreads();
        float sTot = 0.f;
        if (tid < 128) sTot = red_s[tid] + red_s[tid + 128];
        __syncthreads();
        red_s[tid] = qs;
        __syncthreads();
        if (tid < 128) {
            const float qTot = red_s[tid] + red_s[tid + 128];
            const int copy = tileM & (NC - 1);
            atomicAdd(&statsOut[copy * 256 + rowB + colL], sTot);
            atomicAdd(&statsOut[(NC + copy) * 256 + rowB + colL], qTot);
        }
    }

#pragma unroll
    for (int it = 0; it < 4; it++) {
        const int r  = it * 16 + (tid >> 4);
        const int c8 = (tid & 15) * 8;
        *(s16x8*)(C + (rowA + r) * 256 + rowB + c8) = *(const s16x8*)(Cs + r * 128 + c8);
    }
}

template<int AM, bool EXTA, int STATS>
__global__ __launch_bounds__(256) void gemm_k(
    const u16* A, const float* Af, const u16* A2, const u16* Qd,
    const u16* Wb, const void* bias, const void* g, const void* be, int hoff,
    const float* statsIn, float* statsOut, const int* dflag, u16* C)
{
    const int f32in = (*dflag == 0);
    gemm_core<AM, EXTA, STATS>(A, Af, A2, Qd, Wb,
        (const u16*)bias + hoff, (const float*)bias + hoff,
        (const u16*)g + hoff,    (const float*)g + hoff,
        (const u16*)be + hoff,   (const float*)be + hoff,
        statsIn, statsOut, f32in, C, blockIdx.x);
}

template<bool EXTA>
__global__ __launch_bounds__(256) void proj2_k(
    const u16* A0, const float* A0f, const u16* W0, const void* b0, u16* C0,
    const u16* A1, const float* A1f, const u16* W1, const void* b1, u16* C1,
    int hoff, const int* dflag)
{
    const int f32in = (*dflag == 0);
    const int y = blockIdx.y;
    gemm_core<0, EXTA, 0>(
        y ? A1 : A0, y ? A1f : A0f, nullptr, nullptr, y ? W1 : W0,
        (const u16*)(y ? b1 : b0) + hoff, (const float*)(y ? b1 : b0) + hoff,
        nullptr, nullptr, nullptr, nullptr, nullptr, nullptr,
        f32in, y ? C1 : C0, blockIdx.x);
}

// ---------------------------------------------------------------------------
// Online softmax over S + weighted v-sum: 32 chunks x 64 s-rows.
// ---------------------------------------------------------------------------
__global__ __launch_bounds__(256) void softmax_chunk_k(
    const u16* __restrict__ L, const u16* __restrict__ V,
    float* __restrict__ pm, float* __restrict__ pl, float* __restrict__ pa)
{
    const int d = threadIdx.x, b = blockIdx.x, ch = blockIdx.y;
    float m = -3.0e38f, l = 0.f, acc = 0.f;
    const long base = ((long)ch * 64 * 32 + b) * 256 + d;
    for (int si = 0; si < 64; si++) {
        const long idx = base + (long)si * 32 * 256;
        const float x = bu2f(L[idx]);
        const float v = bu2f(V[idx]);
        const float mn = fmaxf(m, x);
        const float c  = __expf(m - mn);
        const float e  = __expf(x - mn);
        l   = l * c + e;
        acc = acc * c + e * v;
        m = mn;
    }
    const int p = (ch * 32 + b) * 256 + d;
    pm[p] = m; pl[p] = l; pa[p] = acc;
}

__global__ __launch_bounds__(256) void softmax_merge_k(
    const float* __restrict__ pm, const float* __restrict__ pl,
    const float* __restrict__ pa, float* __restrict__ xcat, int head)
{
    const int d = threadIdx.x, b = blockIdx.x;
    float M = -3.0e38f, L = 0.f, A = 0.f;
    for (int ch = 0; ch < 32; ch++) {
        const int p = (ch * 32 + b) * 256 + d;
        const float m = pm[p], l = pl[p], a = pa[p];
        const float mn = fmaxf(M, m);
        const float c1 = __expf(M - mn), c2 = __expf(m - mn);
        L = L * c1 + l * c2;
        A = A * c1 + a * c2;
        M = mn;
    }
    xcat[b * 1024 + head * 256 + d] = A / L;
}

// ---------------------------------------------------------------------------
// Final MLP: [32,1024] -> relu -> 256 -> relu -> 256.
// ---------------------------------------------------------------------------
__global__ __launch_bounds__(256) void mlp_k(
    const float* __restrict__ xcat,
    const u16* __restrict__ mw0, const float* __restrict__ mw0f,
    const u16* __restrict__ mb0, const float* __restrict__ mb0f,
    const u16* __restrict__ mw1, const float* __restrict__ mw1f,
    const u16* __restrict__ mb1, const float* __restrict__ mb1f,
    const u16* __restrict__ mw2, const float* __restrict__ mw2f,
    const u16* __restrict__ mb2, const float* __restrict__ mb2f,
    const int* __restrict__ dflag,
    u16* __restrict__ out, float* __restrict__ outf)
{
    __shared__ float h0[1024];
    __shared__ float h1[256];
    __shared__ float h2[256];
    const int f32in = (*dflag == 0);
    const int j = threadIdx.x, b = blockIdx.x;
#pragma unroll
    for (int i = 0; i < 4; i++) h0[j + i * 256] = xcat[b * 1024 + j + i * 256];
    __syncthreads();

    float a0 = f32in ? mb0f[j] : bu2f(mb0[j]);
    if (f32in) {
        for (int k4 = 0; k4 < 256; k4++) {
            f32x4 wv = *(const f32x4*)(mw0f + j * 1024 + k4 * 4);
#pragma unroll
            for (int e = 0; e < 4; e++) a0 += h0[k4 * 4 + e] * wv[e];
        }
    } else {
        for (int k8 = 0; k8 < 128; k8++) {
            s16x8 wv = *(const s16x8*)(mw0 + j * 1024 + k8 * 8);
#pragma unroll
            for (int e = 0; e < 8; e++) a0 += h0[k8 * 8 + e] * bs2f(wv[e]);
        }
    }
    h1[j] = fmaxf(a0, 0.f);
    __syncthreads();

    float a1 = f32in ? mb1f[j] : bu2f(mb1[j]);
    if (f32in) {
        for (int k4 = 0; k4 < 64; k4++) {
            f32x4 wv = *(const f32x4*)(mw1f + j * 256 + k4 * 4);
#pragma unroll
            for (int e = 0; e < 4; e++) a1 += h1[k4 * 4 + e] * wv[e];
        }
    } else {
        for (int k8 = 0; k8 < 32; k8++) {
            s16x8 wv = *(const s16x8*)(mw1 + j * 256 + k8 * 8);
#pragma unroll
            for (int e = 0; e < 8; e++) a1 += h1[k8 * 8 + e] * bs2f(wv[e]);
        }
    }
    h2[j] = fmaxf(a1, 0.f);
    __syncthreads();

    float a2 = f32in ? mb2f[j] : bu2f(mb2[j]);
    if (f32in) {
        for (int k4 = 0; k4 < 64; k4++) {
            f32x4 wv = *(const f32x4*)(mw2f + j * 256 + k4 * 4);
#pragma unroll
            for (int e = 0; e < 4; e++) a2 += h2[k4 * 4 + e] * wv[e];
        }
    } else {
        for (int k8 = 0; k8 < 32; k8++) {
            s16x8 wv = *(const s16x8*)(mw2 + j * 256 + k8 * 8);
#pragma unroll
            for (int e = 0; e < 8; e++) a2 += h2[k8 * 8 + e] * bs2f(wv[e]);
        }
    }
    if (f32in) outf[b * 256 + j] = a2;
    else       out[b * 256 + j] = f2bu(a2);
}

// ---------------------------------------------------------------------------
extern "C" void kernel_launch(void* const* d_in, const int* in_sizes, int n_in,
                              void* d_out, int out_size, void* d_ws, size_t ws_size,
                              hipStream_t stream)
{
    const u16 *q16 = (const u16*)d_in[0], *k16 = (const u16*)d_in[1], *v16 = (const u16*)d_in[2];
    const float *qf = (const float*)d_in[0], *kf = (const float*)d_in[1], *vf = (const float*)d_in[2];

    const size_t TEN = 33554432ull;          // one [65536,256] bf16 tensor
    const size_t WBF_OFF = 2097152ull;       // bf16 weights at 2 MB
    const size_t BUF_OFF = 5242880ull;       // big buffers at 5 MB
    if (ws_size < BUF_OFF + 5 * TEN) return; // 165 MB

    char* ws = (char*)d_ws;
    int*   dflag = (int*)ws;
    float* fb    = (float*)ws;
    float* sums  = fb + 256;                 // 8 arrays x [2*NC][256] = 64K floats
    float* xcat  = sums + 8 * 2 * NC * 256;  // 32 x 1024
    u16*   wbf   = (u16*)(ws + WBF_OFF);     // 5 x [4,256,256] bf16
    u16* buf[5];
    for (int i = 0; i < 5; i++) buf[i] = (u16*)(ws + BUF_OFF + (size_t)i * TEN);

    // per-head buffer rotation (liveness-checked)
    const int qsrc[4] = {-1, 0, 3, 1}, qdst[4] = {0, 3, 1, 4};
    const int ksrc[4] = {-1, 1, 4, 2}, kdst[4] = {1, 4, 2, 0};
    const int vsrc[4] = {-1, 2, 0, 3}, vdst[4] = {2, 0, 3, 1};
    const int x1i[4]  = {3, 1, 4, 2},  lgi[4]  = {4, 2, 0, 3};

    detect_k<<<dim3(1), dim3(256), 0, stream>>>((const unsigned int*)d_in[0], dflag);
    hipMemsetAsync(sums, 0, 8 * 2 * NC * 256 * sizeof(float), stream);
    // slots: 0 wq, 1 wk, 2 wv, 3 wl1, 4 wl2
    wconv_k<<<dim3(256, 5), dim3(256), 0, stream>>>(
        d_in[3], d_in[5], d_in[7], d_in[11], d_in[15], dflag, wbf);

    for (int h = 0; h < 4; h++) {
        const u16* qi = h ? (const u16*)buf[qsrc[h]] : q16;
        const u16* ki = h ? (const u16*)buf[ksrc[h]] : k16;
        const u16* vi = h ? (const u16*)buf[vsrc[h]] : v16;
        u16* qo = buf[qdst[h]];
        u16* ko = buf[kdst[h]];
        u16* vo = buf[vdst[h]];
        u16* x1b = buf[x1i[h]];
        u16* lgb = buf[lgi[h]];
        const u16* Wq  = wbf + (0 * 4 + h) * 65536;
        const u16* Wk  = wbf + (1 * 4 + h) * 65536;
        const u16* Wv  = wbf + (2 * 4 + h) * 65536;
        const u16* Wl1 = wbf + (3 * 4 + h) * 65536;
        const u16* Wl2 = wbf + (4 * 4 + h) * 65536;
        float* st1 = sums + (h * 2 + 0) * 2 * NC * 256;
        float* st2 = sums + (h * 2 + 1) * 2 * NC * 256;
        float* parts = (float*)x1b;   // x1b dead during softmax; 3 MB partials
        const int hoff = h * 256;

        if (h == 0)
            proj2_k<true><<<dim3(2048, 2), dim3(256), 0, stream>>>(
                q16, qf, Wq, d_in[4], qo, v16, vf, Wv, d_in[8], vo, hoff, dflag);
        else
            proj2_k<false><<<dim3(2048, 2), dim3(256), 0, stream>>>(
                qi, nullptr, Wq, d_in[4], qo, vi, nullptr, Wv, d_in[8], vo, hoff, dflag);

        if (h == 0)
            gemm_k<0, true, 1><<<dim3(2048), dim3(256), 0, stream>>>(
                k16, kf, nullptr, qo, Wk, d_in[6], d_in[6], d_in[6], hoff,
                nullptr, st1, dflag, ko);
        else
            gemm_k<0, false, 1><<<dim3(2048), dim3(256), 0, stream>>>(
                ki, nullptr, nullptr, qo, Wk, d_in[6], d_in[6], d_in[6], hoff,
                nullptr, st1, dflag, ko);

        gemm_k<1, false, 2><<<dim3(2048), dim3(256), 0, stream>>>(
            ko, nullptr, qo, nullptr, Wl1, d_in[12], d_in[9], d_in[10], hoff,
            st1, st2, dflag, x1b);

        gemm_k<2, false, 0><<<dim3(2048), dim3(256), 0, stream>>>(
            x1b, nullptr, nullptr, nullptr, Wl2, d_in[16], d_in[13], d_in[14], hoff,
            st2, nullptr, dflag, lgb);

        softmax_chunk_k<<<dim3(32, 32), dim3(256), 0, stream>>>(
            lgb, vo, parts, parts + 262144, parts + 524288);
        softmax_merge_k<<<dim3(32), dim3(256), 0, stream>>>(
            parts, parts + 262144, parts + 524288, xcat, h);
    }
    mlp_k<<<dim3(32), dim3(256), 0, stream>>>(
        xcat,
        (const u16*)d_in[17], (const float*)d_in[17],
        (const u16*)d_in[18], (const float*)d_in[18],
        (const u16*)d_in[19], (const float*)d_in[19],
        (const u16*)d_in[20], (const float*)d_in[20],
        (const u16*)d_in[21], (const float*)d_in[21],
        (const u16*)d_in[22], (const float*)d_in[22],
        dflag, (u16*)d_out, (float*)d_out);
}